// Round 6
// baseline (93011.578 us; speedup 1.0000x reference)
//
#include <hip/hip_runtime.h>
#include <stdint.h>
#include <math.h>

// Persistent barrier-free 2-layer LSTM rollout, MI355X (gfx950).
// R6: producer/consumer wave specialization.
// 512 WGs x 128 thr = 2 waves: wave0 computes (owns h-units {2w,2w+1}),
// wave1 is a dedicated poller that spins on the global h-slot buffers,
// stages fresh vectors into double-buffered LDS, and signals wave0 via
// LDS tag flags (workgroup acquire/release). Wave0 never touches the
// fabric except to publish its 8B {2xf16 | u32 tag} slot per phase.
// Single (non-replicated) 512-slot global buffers; overwrite safety by
// dataflow (tag t+2 publish implies all pollers staged tag t).

#define H     1024
#define NSTEP 8192
#define NWG   512
#define BLK   128
#define NROW  25   // 0-7 Wih1, 8-15 Whh0, 16-23 Whh1, 24 W2

typedef _Float16 h2 __attribute__((ext_vector_type(2)));
typedef _Float16 h8 __attribute__((ext_vector_type(8)));
typedef unsigned long long u64;

union U32H2 { uint32_t u; h2 v; };

__device__ __forceinline__ u64 pack2(float v0, float v1, uint32_t tag){
  U32H2 p; p.v.x = (_Float16)v0; p.v.y = (_Float16)v1;
  return ((u64)tag << 32) | (u64)p.u;
}

// Exact JAX threefry2x32.
__device__ __forceinline__ uint2 tf2x32(uint32_t k0, uint32_t k1, uint32_t x0, uint32_t x1){
  uint32_t k2 = k0 ^ k1 ^ 0x1BD11BDAu;
  x0 += k0; x1 += k1;
#define TFR(r) { x0 += x1; x1 = (x1 << (r)) | (x1 >> (32 - (r))); x1 ^= x0; }
  TFR(13) TFR(15) TFR(26) TFR(6)
  x0 += k1; x1 += k2 + 1u;
  TFR(17) TFR(29) TFR(16) TFR(24)
  x0 += k2; x1 += k0 + 2u;
  TFR(13) TFR(15) TFR(26) TFR(6)
  x0 += k0; x1 += k1 + 3u;
  TFR(17) TFR(29) TFR(16) TFR(24)
  x0 += k1; x1 += k2 + 4u;
  TFR(13) TFR(15) TFR(26) TFR(6)
  x0 += k2; x1 += k0 + 5u;
#undef TFR
  uint2 r; r.x = x0; r.y = x1; return r;
}

// keys = threefry_split(key(42), 8192)
__device__ __forceinline__ uint32_t jax_word(uint32_t i){
  return (i < 8192u) ? tf2x32(0u, 42u, i, i + 8192u).x
                     : tf2x32(0u, 42u, i - 8192u, i).y;
}

__device__ __forceinline__ float wred64(float x){
  #pragma unroll
  for(int off = 32; off > 0; off >>= 1) x += __shfl_xor(x, off, 64);
  return x;
}

// Merge-tree reduce of 8 per-lane partials over 64 lanes; results broadcast.
__device__ __forceinline__ void mreduce8(int lane, const float* v, float* s){
  const bool b1 = lane & 1;
  float t, w0, w1, w2, w3;
  t = b1 ? v[0] : v[1]; w0 = (b1 ? v[1] : v[0]) + __shfl_xor(t, 1, 64);
  t = b1 ? v[2] : v[3]; w1 = (b1 ? v[3] : v[2]) + __shfl_xor(t, 1, 64);
  t = b1 ? v[4] : v[5]; w2 = (b1 ? v[5] : v[4]) + __shfl_xor(t, 1, 64);
  t = b1 ? v[6] : v[7]; w3 = (b1 ? v[7] : v[6]) + __shfl_xor(t, 1, 64);
  const bool b2 = lane & 2;
  float u0, u1;
  t = b2 ? w0 : w1; u0 = (b2 ? w1 : w0) + __shfl_xor(t, 2, 64);
  t = b2 ? w2 : w3; u1 = (b2 ? w3 : w2) + __shfl_xor(t, 2, 64);
  const bool b4 = lane & 4;
  t = b4 ? u0 : u1; float z = (b4 ? u1 : u0) + __shfl_xor(t, 4, 64);
  z += __shfl_xor(z, 8, 64);
  z += __shfl_xor(z, 16, 64);
  z += __shfl_xor(z, 32, 64);
  #pragma unroll
  for(int r = 0; r < 8; r++) s[r] = __shfl(z, r, 64);
}

#if __has_builtin(__builtin_amdgcn_fdot2)
__device__ __forceinline__ float fdot2f(h2 a, h2 b, float c){ return __builtin_amdgcn_fdot2(a, b, c, false); }
#else
__device__ __forceinline__ float fdot2f(h2 a, h2 b, float c){
  return (float)a.x * (float)b.x + (float)a.y * (float)b.y + c;
}
#endif

__device__ __forceinline__ float sigm(float x){
  x = fminf(fmaxf(x, -30.f), 30.f);
  return 1.f / (1.f + __expf(-x));
}
__device__ __forceinline__ float tanh_f(float x){
  x = fminf(fmaxf(x, -15.f), 15.f);
  float e = __expf(2.f * x);
  return (e - 1.f) / (e + 1.f);
}

__device__ __forceinline__ u64 ld_slot(const u64* p){
  return __hip_atomic_load((u64*)p, __ATOMIC_RELAXED, __HIP_MEMORY_SCOPE_AGENT);
}
__device__ __forceinline__ void st_slot(u64* p, u64 v){
  __hip_atomic_store(p, v, __ATOMIC_RELAXED, __HIP_MEMORY_SCOPE_AGENT);
}

// Poller: spin until all 8 of this lane's slots carry `tag`, then write the
// 4B payloads into LDS staging (two b128 stores).
__device__ __forceinline__ void stage_poll(const u64* __restrict__ buf, uint32_t tag,
                                           uint32_t* __restrict__ dst, int lane){
  const u64* p0 = buf + (lane << 2);
  const u64* p1 = buf + 256 + (lane << 2);
  u64 pv[8];
  #pragma unroll
  for(int k = 0; k < 4; k++) pv[k]     = ld_slot(p0 + k);
  #pragma unroll
  for(int k = 0; k < 4; k++) pv[4 + k] = ld_slot(p1 + k);
  for(;;){
    uint32_t bad = 0;
    #pragma unroll
    for(int k = 0; k < 8; k++) bad |= ((uint32_t)(pv[k] >> 32)) ^ tag;
    if(!bad) break;
    #pragma unroll
    for(int k = 0; k < 4; k++) if(((uint32_t)(pv[k] >> 32)) != tag)   pv[k]   = ld_slot(p0 + k);
    #pragma unroll
    for(int k = 0; k < 4; k++) if(((uint32_t)(pv[4+k] >> 32)) != tag) pv[4+k] = ld_slot(p1 + k);
  }
  uint4 a; a.x = (uint32_t)pv[0]; a.y = (uint32_t)pv[1]; a.z = (uint32_t)pv[2]; a.w = (uint32_t)pv[3];
  uint4 b; b.x = (uint32_t)pv[4]; b.y = (uint32_t)pv[5]; b.z = (uint32_t)pv[6]; b.w = (uint32_t)pv[7];
  *(uint4*)(dst + (lane << 2))       = a;
  *(uint4*)(dst + 256 + (lane << 2)) = b;
}

// Compute wave: load staged vector from LDS into registers.
__device__ __forceinline__ void ld_hv(const uint32_t* __restrict__ src, int lane, h2* hv){
  uint4 a = *(const uint4*)(src + (lane << 2));
  uint4 b = *(const uint4*)(src + 256 + (lane << 2));
  U32H2 p;
  p.u = a.x; hv[0] = p.v;  p.u = a.y; hv[1] = p.v;
  p.u = a.z; hv[2] = p.v;  p.u = a.w; hv[3] = p.v;
  p.u = b.x; hv[4] = p.v;  p.u = b.y; hv[5] = p.v;
  p.u = b.z; hv[6] = p.v;  p.u = b.w; hv[7] = p.v;
}

// Row dot partial: lane l covers h2 [4l,4l+4) and [256+4l,+4).
__device__ __forceinline__ float row_part(const h2* __restrict__ wrow, int lane, const h2* hv){
  h8 wl = *(const h8*)(wrow + (lane << 2));
  h8 wh = *(const h8*)(wrow + 256 + (lane << 2));
  float a0 = 0.f, a1 = 0.f;
  h2 w;
  w = __builtin_shufflevector(wl, wl, 0, 1); a0 = fdot2f(w, hv[0], a0);
  w = __builtin_shufflevector(wl, wl, 2, 3); a1 = fdot2f(w, hv[1], a1);
  w = __builtin_shufflevector(wl, wl, 4, 5); a0 = fdot2f(w, hv[2], a0);
  w = __builtin_shufflevector(wl, wl, 6, 7); a1 = fdot2f(w, hv[3], a1);
  w = __builtin_shufflevector(wh, wh, 0, 1); a0 = fdot2f(w, hv[4], a0);
  w = __builtin_shufflevector(wh, wh, 2, 3); a1 = fdot2f(w, hv[5], a1);
  w = __builtin_shufflevector(wh, wh, 4, 5); a0 = fdot2f(w, hv[6], a0);
  w = __builtin_shufflevector(wh, wh, 6, 7); a1 = fdot2f(w, hv[7], a1);
  return a0 + a1;
}

__global__ void __launch_bounds__(BLK)
lstm_persist(const float* __restrict__ ctx,  const float* __restrict__ W1p,  const float* __restrict__ b1p,
             const float* __restrict__ Wih0, const float* __restrict__ Whh0,
             const float* __restrict__ bih0, const float* __restrict__ bhh0,
             const float* __restrict__ Wih1, const float* __restrict__ Whh1,
             const float* __restrict__ bih1, const float* __restrict__ bhh1,
             const float* __restrict__ W2p,  const float* __restrict__ b2p,
             float* __restrict__ out,
             u64* __restrict__ h0buf,   // [512] h0 slots
             u64* __restrict__ h1buf)   // [512] h1 slots
{
  __shared__ h2 w[NROW][H/2];            // 51.2 KB
  __shared__ uint32_t stg[2][2][H/2];    // [vec h0/h1][parity][512] : 8 KB
  __shared__ int flg[2][2];              // staged tag per [vec][parity]
  __shared__ int done[2];                // wave0 consumed tag per vec

  const int tid  = threadIdx.x;
  const int wv   = tid >> 6;
  const int lane = tid & 63;
  const int wg   = blockIdx.x;
  const int j0   = wg << 1;

  if(tid == 0){ flg[0][0] = flg[0][1] = flg[1][0] = flg[1][1] = 0; done[0] = done[1] = 0; }

  // ---- one-time: stage 25 rows as f16 (all 128 threads, coalesced float4)
  #pragma unroll 1
  for(int r = 0; r < NROW; r++){
    const float* rowp;
    if(r < 8)      { int g = r & 3,  j = j0 + (r >> 2);                   rowp = Wih1 + (size_t)(g*H + j)*H; }
    else if(r < 16){ int rr = r - 8;  int g = rr & 3, j = j0 + (rr >> 2); rowp = Whh0 + (size_t)(g*H + j)*H; }
    else if(r < 24){ int rr = r - 16; int g = rr & 3, j = j0 + (rr >> 2); rowp = Whh1 + (size_t)(g*H + j)*H; }
    else           rowp = W2p;
    const float4* s4 = (const float4*)rowp;
    #pragma unroll
    for(int it = 0; it < 2; it++){
      float4 f = s4[tid + (it << 7)];
      h2 pa; pa.x = (_Float16)f.x; pa.y = (_Float16)f.y;
      h2 pb; pb.x = (_Float16)f.z; pb.y = (_Float16)f.w;
      const int ci = (tid + (it << 7)) << 1;
      w[r][ci] = pa; w[r][ci + 1] = pb;
    }
  }
  __syncthreads();

  if(wv == 1){
    // ================= POLLER WAVE =================
    #pragma unroll 1
    for(int t = 0; t < NSTEP; t++){
      const int want = t + 1;
      const int p = want & 1;
      // backpressure: don't overwrite a staging buffer wave0 hasn't consumed
      while(__hip_atomic_load(&done[0], __ATOMIC_ACQUIRE, __HIP_MEMORY_SCOPE_WORKGROUP) < want - 2)
        __builtin_amdgcn_s_sleep(1);
      stage_poll(h0buf, (uint32_t)want, &stg[0][p][0], lane);
      __hip_atomic_store(&flg[0][p], want, __ATOMIC_RELEASE, __HIP_MEMORY_SCOPE_WORKGROUP);

      while(__hip_atomic_load(&done[1], __ATOMIC_ACQUIRE, __HIP_MEMORY_SCOPE_WORKGROUP) < want - 2)
        __builtin_amdgcn_s_sleep(1);
      stage_poll(h1buf, (uint32_t)want, &stg[1][p][0], lane);
      __hip_atomic_store(&flg[1][p], want, __ATOMIC_RELEASE, __HIP_MEMORY_SCOPE_WORKGROUP);
    }
  } else {
    // ================= COMPUTE WAVE =================
    float b0g[8], b1g[8], w0g[8];
    #pragma unroll
    for(int e = 0; e < 2; e++){
      const int j = j0 + e;
      #pragma unroll
      for(int g = 0; g < 4; g++){
        b0g[4*e + g] = bih0[g*H + j] + bhh0[g*H + j];
        b1g[4*e + g] = bih1[g*H + j] + bhh1[g*H + j];
        w0g[4*e + g] = Wih0[g*H + j];
      }
    }
    const float b2v = b2p[0];

    // x0 = W1 @ context + b1
    float xacc = 0.f;
    for(int c = lane; c < 512; c += 64) xacc += W1p[c] * ctx[c];
    const float x0 = wred64(xacc) + b1p[0];

    float c0v[2], c1v[2] = {0.f, 0.f}, logp = 0.f;
    float a1[8] = {0.f,0.f,0.f,0.f,0.f,0.f,0.f,0.f};
    float ubatch = 0.f;

    // h0(0) from x0, publish tag 1
    {
      float h00[2];
      #pragma unroll
      for(int e = 0; e < 2; e++){
        float gi = sigm (w0g[4*e+0]*x0 + b0g[4*e+0]);
        float gg = tanh_f(w0g[4*e+2]*x0 + b0g[4*e+2]);
        float go = sigm (w0g[4*e+3]*x0 + b0g[4*e+3]);
        c0v[e] = gi * gg;
        h00[e] = go * tanh_f(c0v[e]);
      }
      if(lane == 0) st_slot(&h0buf[wg], pack2(h00[0], h00[1], 1u));
    }

    h2 hv[8];

    #pragma unroll 1
    for(int t = 0; t < NSTEP; t++){
      const uint32_t tt = (uint32_t)t;
      const int want = t + 1;
      const int p = want & 1;

      // ---- P1: wait for staged h0(t)
      while(__hip_atomic_load(&flg[0][p], __ATOMIC_ACQUIRE, __HIP_MEMORY_SCOPE_WORKGROUP) != want)
        __builtin_amdgcn_s_sleep(1);
      ld_hv(&stg[0][p][0], lane, hv);
      __hip_atomic_store(&done[0], want, __ATOMIC_RELEASE, __HIP_MEMORY_SCOPE_WORKGROUP);

      // critical: 8 layer-1 gate rows -> cell1 -> publish h1(t)
      float pr[8], s1[8];
      #pragma unroll
      for(int r = 0; r < 8; r++) pr[r] = row_part(&w[r][0], lane, hv);
      mreduce8(lane, pr, s1);
      {
        float h1v[2];
        #pragma unroll
        for(int e = 0; e < 2; e++){
          float gi = sigm (s1[4*e+0] + a1[4*e+0] + b1g[4*e+0]);
          float gf = sigm (s1[4*e+1] + a1[4*e+1] + b1g[4*e+1]);
          float gg = tanh_f(s1[4*e+2] + a1[4*e+2] + b1g[4*e+2]);
          float go = sigm (s1[4*e+3] + a1[4*e+3] + b1g[4*e+3]);
          c1v[e] = gf*c1v[e] + gi*gg;
          h1v[e] = go * tanh_f(c1v[e]);
        }
        if(lane == 0) st_slot(&h1buf[wg], pack2(h1v[0], h1v[1], (uint32_t)want));
      }

      // shadow1: RNG refill (1/64), a0 rows, local h0(t+1) candidates
      if((t & 63) == 0){
        const uint32_t i0 = (uint32_t)t + (uint32_t)lane;
        const uint32_t kk0 = jax_word(2u*i0), kk1 = jax_word(2u*i0 + 1u);
        const uint32_t bits = tf2x32(kk0, kk1, 0u, 0u).x;
        ubatch = __uint_as_float((bits >> 9) | 0x3f800000u) - 1.0f;
      }
      float a0p[8], a0[8];
      #pragma unroll
      for(int r = 0; r < 8; r++) a0p[r] = row_part(&w[8 + r][0], lane, hv);
      mreduce8(lane, a0p, a0);

      float c0c[2][2], h0c[2][2];
      #pragma unroll
      for(int e = 0; e < 2; e++){
        #pragma unroll
        for(int sb = 0; sb < 2; sb++){
          const float sv = (float)sb;
          float gi = sigm (a0[4*e+0] + w0g[4*e+0]*sv + b0g[4*e+0]);
          float gf = sigm (a0[4*e+1] + w0g[4*e+1]*sv + b0g[4*e+1]);
          float gg = tanh_f(a0[4*e+2] + w0g[4*e+2]*sv + b0g[4*e+2]);
          float go = sigm (a0[4*e+3] + w0g[4*e+3]*sv + b0g[4*e+3]);
          float cc = gf*c0v[e] + gi*gg;
          c0c[e][sb] = cc;
          h0c[e][sb] = go * tanh_f(cc);
        }
      }

      // ---- P2: wait for staged h1(t)
      while(__hip_atomic_load(&flg[1][p], __ATOMIC_ACQUIRE, __HIP_MEMORY_SCOPE_WORKGROUP) != want)
        __builtin_amdgcn_s_sleep(1);
      ld_hv(&stg[1][p][0], lane, hv);
      __hip_atomic_store(&done[1], want, __ATOMIC_RELEASE, __HIP_MEMORY_SCOPE_WORKGROUP);

      // critical: W2 row -> s -> select -> publish h0(t+1)
      float z = row_part(&w[24][0], lane, hv);
      z = wred64(z) + b2v;
      const float pp = sigm(z);
      const float u = __shfl(ubatch, t & 63, 64);
      const bool  sb_ = (u < pp);
      c0v[0] = sb_ ? c0c[0][1] : c0c[0][0];
      c0v[1] = sb_ ? c0c[1][1] : c0c[1][0];
      if(lane == 0)
        st_slot(&h0buf[wg], pack2(sb_ ? h0c[0][1] : h0c[0][0],
                                  sb_ ? h0c[1][1] : h0c[1][0], tt + 2u));

      logp += sb_ ? __logf(pp) : __logf(1.f - pp);
      if(wg == 0 && lane == 0) out[t] = sb_ ? 1.f : 0.f;

      // shadow2: a1 = Whh1 @ h1(t)
      float a1p[8];
      #pragma unroll
      for(int r = 0; r < 8; r++) a1p[r] = row_part(&w[16 + r][0], lane, hv);
      mreduce8(lane, a1p, a1);
    }

    if(wg == 0 && lane == 0) out[NSTEP] = logp;
  }
}

extern "C" void kernel_launch(void* const* d_in, const int* in_sizes, int n_in,
                              void* d_out, int out_size, void* d_ws, size_t ws_size,
                              hipStream_t stream){
  u64* h0buf = (u64*)d_ws;        // [512]
  u64* h1buf = h0buf + 512;       // [512]
  hipLaunchKernelGGL(lstm_persist, dim3(NWG), dim3(BLK), 0, stream,
    (const float*)d_in[0],  (const float*)d_in[1],  (const float*)d_in[2],
    (const float*)d_in[3],  (const float*)d_in[4],  (const float*)d_in[5],  (const float*)d_in[6],
    (const float*)d_in[7],  (const float*)d_in[8],  (const float*)d_in[9],  (const float*)d_in[10],
    (const float*)d_in[11], (const float*)d_in[12],
    (float*)d_out, h0buf, h1buf);
}

// Round 7
// 65609.283 us; speedup vs baseline: 1.4177x; 1.4177x over previous
//
#include <hip/hip_runtime.h>
#include <stdint.h>
#include <math.h>

// Persistent barrier-free 2-layer LSTM rollout, MI355X (gfx950).
// R7: ONE broadcast phase per step. Slot j (8B, atomic) carries
// {f16 h0cand(t+1)|s=0, f16 h0cand(t+1)|s=1, f16 h1(t), u16 tag}.
// Every wave polls the full 1024-slot vector once per step, computes
// z=W2.h1(t) -> identical Bernoulli s(t) everywhere (bit-identical data
// and code), selects h0(t+1) from the in-slot candidates, computes its
// own 2 units' gates (Wih1@h0 + Whh1@h1 fused) + Whh0 rows + next
// candidates, and publishes the next combined slot. Parity-double-
// buffered; R3's proven sleep-paced stale-only re-poll discipline.

#define H     1024
#define NSTEP 8192
#define NWG   512
#define BLK   64
#define NROW  25   // 0-7 Wih1, 8-15 Whh0, 16-23 Whh1, 24 W2

typedef _Float16 h2 __attribute__((ext_vector_type(2)));
typedef _Float16 h8 __attribute__((ext_vector_type(8)));
typedef unsigned long long u64;

union U32H2 { uint32_t u; h2 v; };
union F16U  { _Float16 h; uint16_t u; };

__device__ __forceinline__ uint32_t f16b(float x){ F16U f; f.h = (_Float16)x; return (uint32_t)f.u; }

// slot = {c0cand | c1cand<<16 | h1<<32 | tag<<48}
__device__ __forceinline__ u64 pack3(float c0c_, float c1c_, float h1_, uint32_t tag){
  return (u64)(f16b(c0c_) | (f16b(c1c_) << 16)) | ((u64)(f16b(h1_) | (tag << 16)) << 32);
}

// Exact JAX threefry2x32.
__device__ __forceinline__ uint2 tf2x32(uint32_t k0, uint32_t k1, uint32_t x0, uint32_t x1){
  uint32_t k2 = k0 ^ k1 ^ 0x1BD11BDAu;
  x0 += k0; x1 += k1;
#define TFR(r) { x0 += x1; x1 = (x1 << (r)) | (x1 >> (32 - (r))); x1 ^= x0; }
  TFR(13) TFR(15) TFR(26) TFR(6)
  x0 += k1; x1 += k2 + 1u;
  TFR(17) TFR(29) TFR(16) TFR(24)
  x0 += k2; x1 += k0 + 2u;
  TFR(13) TFR(15) TFR(26) TFR(6)
  x0 += k0; x1 += k1 + 3u;
  TFR(17) TFR(29) TFR(16) TFR(24)
  x0 += k1; x1 += k2 + 4u;
  TFR(13) TFR(15) TFR(26) TFR(6)
  x0 += k2; x1 += k0 + 5u;
#undef TFR
  uint2 r; r.x = x0; r.y = x1; return r;
}

// keys = threefry_split(key(42), 8192)
__device__ __forceinline__ uint32_t jax_word(uint32_t i){
  return (i < 8192u) ? tf2x32(0u, 42u, i, i + 8192u).x
                     : tf2x32(0u, 42u, i - 8192u, i).y;
}

__device__ __forceinline__ float wred64(float x){
  #pragma unroll
  for(int off = 32; off > 0; off >>= 1) x += __shfl_xor(x, off, 64);
  return x;
}

// Merge-tree reduce of 8 per-lane partials over 64 lanes; results broadcast.
__device__ __forceinline__ void mreduce8(int lane, const float* v, float* s){
  const bool b1 = lane & 1;
  float t, w0, w1, w2, w3;
  t = b1 ? v[0] : v[1]; w0 = (b1 ? v[1] : v[0]) + __shfl_xor(t, 1, 64);
  t = b1 ? v[2] : v[3]; w1 = (b1 ? v[3] : v[2]) + __shfl_xor(t, 1, 64);
  t = b1 ? v[4] : v[5]; w2 = (b1 ? v[5] : v[4]) + __shfl_xor(t, 1, 64);
  t = b1 ? v[6] : v[7]; w3 = (b1 ? v[7] : v[6]) + __shfl_xor(t, 1, 64);
  const bool b2 = lane & 2;
  float u0, u1;
  t = b2 ? w0 : w1; u0 = (b2 ? w1 : w0) + __shfl_xor(t, 2, 64);
  t = b2 ? w2 : w3; u1 = (b2 ? w3 : w2) + __shfl_xor(t, 2, 64);
  const bool b4 = lane & 4;
  t = b4 ? u0 : u1; float z = (b4 ? u1 : u0) + __shfl_xor(t, 4, 64);
  z += __shfl_xor(z, 8, 64);
  z += __shfl_xor(z, 16, 64);
  z += __shfl_xor(z, 32, 64);
  #pragma unroll
  for(int r = 0; r < 8; r++) s[r] = __shfl(z, r, 64);
}

#if __has_builtin(__builtin_amdgcn_fdot2)
__device__ __forceinline__ float fdot2f(h2 a, h2 b, float c){ return __builtin_amdgcn_fdot2(a, b, c, false); }
#else
__device__ __forceinline__ float fdot2f(h2 a, h2 b, float c){
  return (float)a.x * (float)b.x + (float)a.y * (float)b.y + c;
}
#endif

__device__ __forceinline__ float sigm(float x){
  x = fminf(fmaxf(x, -30.f), 30.f);
  return 1.f / (1.f + __expf(-x));
}
__device__ __forceinline__ float tanh_f(float x){
  x = fminf(fmaxf(x, -15.f), 15.f);
  float e = __expf(2.f * x);
  return (e - 1.f) / (e + 1.f);
}

__device__ __forceinline__ u64 ld_slot(const u64* p){
  return __hip_atomic_load((u64*)p, __ATOMIC_RELAXED, __HIP_MEMORY_SCOPE_AGENT);
}
__device__ __forceinline__ void st_slot(u64* p, u64 v){
  __hip_atomic_store(p, v, __ATOMIC_RELAXED, __HIP_MEMORY_SCOPE_AGENT);
}

// Poll this lane's 16 slots (units [8l,8l+8) and [512+8l,+8)); initial
// sweep + sleep-paced stale-only re-sweeps (R3 discipline).
__device__ __forceinline__ void poll16(const u64* __restrict__ buf, uint32_t tag,
                                       int lane, u64* pv){
  const u64* p0 = buf + (lane << 3);
  const u64* p1 = buf + 512 + (lane << 3);
  #pragma unroll
  for(int k = 0; k < 8; k++) pv[k]     = ld_slot(p0 + k);
  #pragma unroll
  for(int k = 0; k < 8; k++) pv[8 + k] = ld_slot(p1 + k);
  for(;;){
    uint32_t bad = 0;
    #pragma unroll
    for(int k = 0; k < 16; k++) bad |= ((uint32_t)(pv[k] >> 48)) ^ tag;
    if(!bad) break;
    __builtin_amdgcn_s_sleep(1);
    #pragma unroll
    for(int k = 0; k < 8; k++) if(((uint32_t)(pv[k] >> 48)) != tag)   pv[k]   = ld_slot(p0 + k);
    #pragma unroll
    for(int k = 0; k < 8; k++) if(((uint32_t)(pv[8+k] >> 48)) != tag) pv[8+k] = ld_slot(p1 + k);
  }
}

// Extract the three f16 vectors from 16 slots into h2 fragments.
__device__ __forceinline__ void extract(const u64* pv, h2* f_c0, h2* f_c1, h2* f_h1){
  #pragma unroll
  for(int g = 0; g < 2; g++){
    #pragma unroll
    for(int m = 0; m < 4; m++){
      const u64 a = pv[8*g + 2*m], b = pv[8*g + 2*m + 1];
      const uint32_t lo_a = (uint32_t)a, lo_b = (uint32_t)b;
      const uint32_t hi_a = (uint32_t)(a >> 32), hi_b = (uint32_t)(b >> 32);
      U32H2 p;
      p.u = (lo_a & 0xffffu) | (lo_b << 16);        f_c0[4*g + m] = p.v;
      p.u = (lo_a >> 16) | (lo_b & 0xffff0000u);    f_c1[4*g + m] = p.v;
      p.u = (hi_a & 0xffffu) | (hi_b << 16);        f_h1[4*g + m] = p.v;
    }
  }
}

// Row dot partial: lane l covers h2 [4l,4l+4) and [256+4l,+4).
__device__ __forceinline__ float row_part(const h2* __restrict__ wrow, int lane, const h2* hv){
  h8 wl = *(const h8*)(wrow + (lane << 2));
  h8 wh = *(const h8*)(wrow + 256 + (lane << 2));
  float a0 = 0.f, a1 = 0.f;
  h2 w;
  w = __builtin_shufflevector(wl, wl, 0, 1); a0 = fdot2f(w, hv[0], a0);
  w = __builtin_shufflevector(wl, wl, 2, 3); a1 = fdot2f(w, hv[1], a1);
  w = __builtin_shufflevector(wl, wl, 4, 5); a0 = fdot2f(w, hv[2], a0);
  w = __builtin_shufflevector(wl, wl, 6, 7); a1 = fdot2f(w, hv[3], a1);
  w = __builtin_shufflevector(wh, wh, 0, 1); a0 = fdot2f(w, hv[4], a0);
  w = __builtin_shufflevector(wh, wh, 2, 3); a1 = fdot2f(w, hv[5], a1);
  w = __builtin_shufflevector(wh, wh, 4, 5); a0 = fdot2f(w, hv[6], a0);
  w = __builtin_shufflevector(wh, wh, 6, 7); a1 = fdot2f(w, hv[7], a1);
  return a0 + a1;
}

__global__ void __launch_bounds__(BLK)
lstm_persist(const float* __restrict__ ctx,  const float* __restrict__ W1p,  const float* __restrict__ b1p,
             const float* __restrict__ Wih0, const float* __restrict__ Whh0,
             const float* __restrict__ bih0, const float* __restrict__ bhh0,
             const float* __restrict__ Wih1, const float* __restrict__ Whh1,
             const float* __restrict__ bih1, const float* __restrict__ bhh1,
             const float* __restrict__ W2p,  const float* __restrict__ b2p,
             float* __restrict__ out,
             u64* __restrict__ sbuf)   // [2][1024] parity-double-buffered combined slots
{
  __shared__ h2 w[NROW][H/2];   // 51.2 KB; 2 WGs/CU co-resident

  const int lane = threadIdx.x;
  const int wg   = blockIdx.x;
  const int j0   = wg << 1;

  // ---- one-time: stage 25 rows as f16 (coalesced float4 reads)
  #pragma unroll 1
  for(int r = 0; r < NROW; r++){
    const float* rowp;
    if(r < 8)      { int g = r & 3,  j = j0 + (r >> 2);                   rowp = Wih1 + (size_t)(g*H + j)*H; }
    else if(r < 16){ int rr = r - 8;  int g = rr & 3, j = j0 + (rr >> 2); rowp = Whh0 + (size_t)(g*H + j)*H; }
    else if(r < 24){ int rr = r - 16; int g = rr & 3, j = j0 + (rr >> 2); rowp = Whh1 + (size_t)(g*H + j)*H; }
    else           rowp = W2p;
    const float4* s4 = (const float4*)rowp;
    #pragma unroll
    for(int it = 0; it < 4; it++){
      float4 f = s4[lane + (it << 6)];
      h2 pa; pa.x = (_Float16)f.x; pa.y = (_Float16)f.y;
      h2 pb; pb.x = (_Float16)f.z; pb.y = (_Float16)f.w;
      const int ci = (lane + (it << 6)) << 1;
      w[r][ci] = pa; w[r][ci + 1] = pb;
    }
  }
  __syncthreads();

  // per-wave scalars (uniform across lanes)
  float b0g[8], b1g[8], w0g[8];
  #pragma unroll
  for(int e = 0; e < 2; e++){
    const int j = j0 + e;
    #pragma unroll
    for(int g = 0; g < 4; g++){
      b0g[4*e + g] = bih0[g*H + j] + bhh0[g*H + j];
      b1g[4*e + g] = bih1[g*H + j] + bhh1[g*H + j];
      w0g[4*e + g] = Wih0[g*H + j];
    }
  }
  const float b2v = b2p[0];

  // x0 = W1 @ context + b1
  float xacc = 0.f;
  for(int c = lane; c < 512; c += 64) xacc += W1p[c] * ctx[c];
  const float x0 = wred64(xacc) + b1p[0];

  float c0v[2], c1v[2] = {0.f, 0.f}, logp = 0.f;
  float c0c[2][2];          // c0 candidates from previous iteration
  float ubatch = 1.f;       // uniform batch (lane m holds u(base+m))

  // ---- bootstrap: h0(0) from x0 (no s-dependence): equal candidates, h1(-1)=0, tag 0
  {
    u64 pk[2];
    #pragma unroll
    for(int e = 0; e < 2; e++){
      float gi = sigm (w0g[4*e+0]*x0 + b0g[4*e+0]);
      float gg = tanh_f(w0g[4*e+2]*x0 + b0g[4*e+2]);
      float go = sigm (w0g[4*e+3]*x0 + b0g[4*e+3]);
      float cc = gi * gg;
      c0c[e][0] = c0c[e][1] = cc;
      float h00 = go * tanh_f(cc);
      pk[e] = pack3(h00, h00, 0.f, 0u);
    }
    if(lane < 2) st_slot(&sbuf[j0 + lane], pk[lane]);
  }

  #pragma unroll 1
  for(int t = 0; t <= NSTEP; t++){
    const uint32_t tag = (uint32_t)t & 0xffffu;
    const u64* rbuf = sbuf + ((t & 1) << 10);

    // ---- poll combined slot(t): {h0cands(t), h1(t-1)}
    u64 pv[16];
    poll16(rbuf, tag, lane, pv);
    h2 f_c0[8], f_c1[8], f_h1[8];
    extract(pv, f_c0, f_c1, f_h1);

    // ---- z(t-1) = W2 . h1(t-1)  -> p -> s(t-1)  (identical on all waves)
    float z = row_part(&w[24][0], lane, f_h1);
    z = wred64(z) + b2v;
    const float p = sigm(z);
    const int idx = t - 1;
    if(t >= 1 && (idx & 63) == 0){
      const uint32_t i0 = (uint32_t)idx + (uint32_t)lane;
      const uint32_t kk0 = jax_word(2u*i0), kk1 = jax_word(2u*i0 + 1u);
      const uint32_t bits = tf2x32(kk0, kk1, 0u, 0u).x;
      ubatch = __uint_as_float((bits >> 9) | 0x3f800000u) - 1.0f;
    }
    const float u = (t >= 1) ? __shfl(ubatch, idx & 63, 64) : 1.f;
    const bool  sb_ = (u < p);

    if(t == NSTEP){
      logp += sb_ ? __logf(p) : __logf(1.f - p);
      if(wg == 0 && lane == 0){ out[NSTEP - 1] = sb_ ? 1.f : 0.f; out[NSTEP] = logp; }
      break;
    }

    // ---- select h0(t) fragment + own c0(t)
    h2 hv0[8];
    #pragma unroll
    for(int k = 0; k < 8; k++) hv0[k] = sb_ ? f_c1[k] : f_c0[k];
    c0v[0] = sb_ ? c0c[0][1] : c0c[0][0];
    c0v[1] = sb_ ? c0c[1][1] : c0c[1][0];

    // ---- layer-1 gates: Wih1@h0(t) + Whh1@h1(t-1), fused partials
    float pr[8], s1[8];
    #pragma unroll
    for(int r = 0; r < 8; r++)
      pr[r] = row_part(&w[r][0], lane, hv0) + row_part(&w[16 + r][0], lane, f_h1);
    mreduce8(lane, pr, s1);
    float h1v[2];
    #pragma unroll
    for(int e = 0; e < 2; e++){
      float gi = sigm (s1[4*e+0] + b1g[4*e+0]);
      float gf = sigm (s1[4*e+1] + b1g[4*e+1]);
      float gg = tanh_f(s1[4*e+2] + b1g[4*e+2]);
      float go = sigm (s1[4*e+3] + b1g[4*e+3]);
      c1v[e] = gf*c1v[e] + gi*gg;
      h1v[e] = go * tanh_f(c1v[e]);
    }

    // ---- a0 = Whh0 @ h0(t) -> h0(t+1) candidates for both s outcomes
    float a0p[8], a0[8];
    #pragma unroll
    for(int r = 0; r < 8; r++) a0p[r] = row_part(&w[8 + r][0], lane, hv0);
    mreduce8(lane, a0p, a0);

    float h0c[2][2];
    #pragma unroll
    for(int e = 0; e < 2; e++){
      #pragma unroll
      for(int sb2 = 0; sb2 < 2; sb2++){
        const float sv = (float)sb2;
        float gi = sigm (a0[4*e+0] + w0g[4*e+0]*sv + b0g[4*e+0]);
        float gf = sigm (a0[4*e+1] + w0g[4*e+1]*sv + b0g[4*e+1]);
        float gg = tanh_f(a0[4*e+2] + w0g[4*e+2]*sv + b0g[4*e+2]);
        float go = sigm (a0[4*e+3] + w0g[4*e+3]*sv + b0g[4*e+3]);
        float cc = gf*c0v[e] + gi*gg;
        c0c[e][sb2] = cc;
        h0c[e][sb2] = go * tanh_f(cc);
      }
    }

    // ---- publish combined slot(t+1)
    {
      u64* wbuf = sbuf + (((t + 1) & 1) << 10);
      u64 pk0 = pack3(h0c[0][0], h0c[0][1], h1v[0], (uint32_t)(t + 1) & 0xffffu);
      u64 pk1 = pack3(h0c[1][0], h0c[1][1], h1v[1], (uint32_t)(t + 1) & 0xffffu);
      if(lane < 2) st_slot(&wbuf[j0 + lane], lane ? pk1 : pk0);
    }

    // ---- off-chain: logp + sample output for step t-1
    if(t >= 1){
      logp += sb_ ? __logf(p) : __logf(1.f - p);
      if(wg == 0 && lane == 0) out[t - 1] = sb_ ? 1.f : 0.f;
    }
  }
}

extern "C" void kernel_launch(void* const* d_in, const int* in_sizes, int n_in,
                              void* d_out, int out_size, void* d_ws, size_t ws_size,
                              hipStream_t stream){
  u64* sbuf = (u64*)d_ws;   // [2][1024] = 16 KB
  hipLaunchKernelGGL(lstm_persist, dim3(NWG), dim3(BLK), 0, stream,
    (const float*)d_in[0],  (const float*)d_in[1],  (const float*)d_in[2],
    (const float*)d_in[3],  (const float*)d_in[4],  (const float*)d_in[5],  (const float*)d_in[6],
    (const float*)d_in[7],  (const float*)d_in[8],  (const float*)d_in[9],  (const float*)d_in[10],
    (const float*)d_in[11], (const float*)d_in[12],
    (float*)d_out, sbuf);
}